// Round 6
// baseline (254.269 us; speedup 1.0000x reference)
//
#include <hip/hip_runtime.h>
#include <math.h>

// SpanPairVAHead on MI355X (gfx950).
// Dtype map (established rounds 0-3): ALL float tensors f32, spans int
// (32/64 sniffed on device), OUTPUT f32. Internal activations bf16 for MFMA.
//
// R6: pool re-tiled to 64-col slices (1024 blocks, 4/CU, LDS 35KB union,
// launch_bounds(256,4)) — it is latency-bound (VALU total ~2.4us, mem floor
// ~21us), so occupancy x2 + shorter load chains. Split-K reduce fused into
// gemm2_head (reads P directly, +b1+gelu at A-staging). 4 launches.
//
// B=64, L=512, H=1024, Q=64, VA_H=256. Pairs = B*Q = 4096.

typedef __attribute__((ext_vector_type(4))) float f32x4;
typedef __attribute__((ext_vector_type(8))) short bf16x8;

#define NPAIR 4096
#define LSEQ 512
#define HDIM 1024

// Pack two f32 -> bf16 pair, round-to-nearest (half-up; ties-up vs RNE only
// at p~2^-16). v_perm_b32 grabs the two high halves in one instruction.
__device__ __forceinline__ unsigned int pack2(float lo, float hi) {
  const unsigned int a = __float_as_uint(lo) + 0x8000u;
  const unsigned int b = __float_as_uint(hi) + 0x8000u;
  return __builtin_amdgcn_perm(b, a, 0x07060302u);
}
__device__ __forceinline__ unsigned short f2bf(float f) {
  return (unsigned short)((__float_as_uint(f) + 0x8000u) >> 16);
}
__device__ __forceinline__ float gelu(float x) {
  return 0.5f * x * (1.f + erff(x * 0.70710678118654752f));
}

// ---------------------------------------------------------------------------
// Fused span pooling via MFMA. One block per (batch, 64-col H-slice):
// 1024 blocks = 4/CU exact residency. Rows 0..63 = asp masks, 64..127 = opi.
// A-frags from span compares in registers; B staged f32->bf16 transposed
// ([n][k]) double-buffered, 1 barrier/iter. Epilogue S[128][68] unions with
// Bl (LDS ~35KB -> 4 blocks/CU).
// ---------------------------------------------------------------------------
__global__ __launch_bounds__(256, 4) void pool_mfma_kernel(
    const float* __restrict__ hs, const int* __restrict__ spans,
    const int* __restrict__ qmask, unsigned short* __restrict__ hpair) {
  __shared__ __align__(16) unsigned char smem[34816];  // max(2*64*40*2, 128*68*4)
  __shared__ float scl[128];
  typedef unsigned short BlT[64][40];
  BlT* Bl = (BlT*)smem;                  // Bl[2][64][40]
  float(*S)[68] = (float(*)[68])smem;    // S[128][68] (epilogue only)

  const int b = blockIdx.x >> 4;
  const int n0 = (blockIdx.x & 15) * 64;
  const int tid = threadIdx.x;
  const int lane = tid & 63;
  const int lm = lane & 15, quad = lane >> 4;
  const int wm = (tid >> 6) * 32;  // wave's mask-row base

  const bool is64 =
      (spans[1] == 0) && (spans[3] == 0) && (spans[5] == 0) && (spans[7] == 0);

  auto span_of = [&](int r, int& s, int& e) {
    const int q = r & 63, t = r >> 6;
    const int idx = (b * 64 + q) * 4 + t * 2;
    s = is64 ? spans[idx * 2] : spans[idx];
    e = is64 ? spans[idx * 2 + 2] : spans[idx + 1];
    if (s < 2) { s = 1; e = 1; }  // invalid -> [SEP]
  };
  int s0, e0, s1, e1;
  span_of(wm + lm, s0, e0);
  span_of(wm + 16 + lm, s1, e1);

  if (tid < 128) {
    int s, e;
    span_of(tid, s, e);
    const int c = (e >= s) ? (e - s + 1) : 0;
    const float sc = 1.f / (float)(c < 1 ? 1 : c);
    scl[tid] = (qmask[b * 64 + (tid & 63)] != 0) ? sc : 0.f;
  }

  f32x4 acc[2][4];
#pragma unroll
  for (int f = 0; f < 2; ++f)
#pragma unroll
    for (int g = 0; g < 4; ++g) acc[f][g] = f32x4{0.f, 0.f, 0.f, 0.f};

  const float* hsb = hs + (size_t)b * (LSEQ * HDIM);
  const int nl = tid & 63;        // staged column (wave-coalesced)
  const int kw = (tid >> 6) * 8;  // wave's k-offset within 32-chunk

  auto load8 = [&](int kbase, unsigned int (&tmp)[4]) {
    const float* src = hsb + (size_t)(kbase + kw) * HDIM + n0 + nl;
#pragma unroll
    for (int i = 0; i < 4; ++i) {
      const float f0 = src[(size_t)(2 * i) * HDIM];
      const float f1 = src[(size_t)(2 * i + 1) * HDIM];
      tmp[i] = pack2(f0, f1);
    }
  };

  unsigned int tmp[4];
  load8(0, tmp);
  *(uint4*)&Bl[0][nl][kw] = make_uint4(tmp[0], tmp[1], tmp[2], tmp[3]);

  for (int it = 0; it < 16; ++it) {
    const int k0 = it * 32;
    __syncthreads();  // buf[it&1] staged; prior reads of buf[(it+1)&1] done
    if (it < 15) load8(k0 + 32, tmp);

    bf16x8 a0, a1;
#pragma unroll
    for (int j = 0; j < 8; ++j) {
      const int k = k0 + quad * 8 + j;
      a0[j] = (short)((k >= s0 && k <= e0) ? 0x3F80 : 0);
      a1[j] = (short)((k >= s1 && k <= e1) ? 0x3F80 : 0);
    }
    const BlT& Bc = Bl[it & 1];
#pragma unroll
    for (int g = 0; g < 4; ++g) {
      bf16x8 bg = *(const bf16x8*)&Bc[g * 16 + lm][quad * 8];
      acc[0][g] = __builtin_amdgcn_mfma_f32_16x16x32_bf16(a0, bg, acc[0][g], 0, 0, 0);
      acc[1][g] = __builtin_amdgcn_mfma_f32_16x16x32_bf16(a1, bg, acc[1][g], 0, 0, 0);
    }
    if (it < 15) {
      *(uint4*)&Bl[(it + 1) & 1][nl][kw] = make_uint4(tmp[0], tmp[1], tmp[2], tmp[3]);
    }
  }

  __syncthreads();  // all MFMA LDS reads done before S overwrites Bl
  // C/D layout (m89): col = lane&15, row = quad*4 + reg.
#pragma unroll
  for (int f = 0; f < 2; ++f)
#pragma unroll
    for (int g = 0; g < 4; ++g)
#pragma unroll
      for (int r = 0; r < 4; ++r)
        S[wm + f * 16 + quad * 4 + r][g * 16 + lm] = acc[f][g][r];
  __syncthreads();

  // Store h_pair: thread q = tid>>2, 16-col group cg = (tid&3)*16.
  const int q = tid >> 2;
  const int cg = (tid & 3) * 16;
  const float sA = scl[q], sO = scl[64 + q];
  unsigned short* dst = hpair + (size_t)(b * 64 + q) * 3072 + n0 + cg;
#pragma unroll
  for (int h = 0; h < 2; ++h) {
    float a[8], o[8];
#pragma unroll
    for (int i = 0; i < 8; ++i) {
      a[i] = S[q][cg + h * 8 + i] * sA;
      o[i] = S[64 + q][cg + h * 8 + i] * sO;
    }
    uint4 wa, wo, wp;
    wa.x = pack2(a[0], a[1]); wa.y = pack2(a[2], a[3]);
    wa.z = pack2(a[4], a[5]); wa.w = pack2(a[6], a[7]);
    wo.x = pack2(o[0], o[1]); wo.y = pack2(o[2], o[3]);
    wo.z = pack2(o[4], o[5]); wo.w = pack2(o[6], o[7]);
    wp.x = pack2(a[0] * o[0], a[1] * o[1]); wp.y = pack2(a[2] * o[2], a[3] * o[3]);
    wp.z = pack2(a[4] * o[4], a[5] * o[5]); wp.w = pack2(a[6] * o[6], a[7] * o[7]);
    *(uint4*)(dst + h * 8) = wa;
    *(uint4*)(dst + 1024 + h * 8) = wo;
    *(uint4*)(dst + 2048 + h * 8) = wp;
  }
}

// ---------------------------------------------------------------------------
// Both weight transposes in one launch. Blocks 0..767: W1 (3072x256);
// 768..799: W2 (256x128). f32 in -> bf16 out, transposed.
// ---------------------------------------------------------------------------
__global__ void transpose_two(const float* __restrict__ W1,
                              unsigned short* __restrict__ W1T,
                              const float* __restrict__ W2,
                              unsigned short* __restrict__ W2T) {
  __shared__ float t[32][33];
  const float* in;
  unsigned short* out;
  int R, C, c0, r0;
  int blk = blockIdx.x;
  if (blk < 768) {
    in = W1; out = W1T; R = 3072; C = 256;
    c0 = (blk & 7) * 32; r0 = (blk >> 3) * 32;
  } else {
    blk -= 768;
    in = W2; out = W2T; R = 256; C = 128;
    c0 = (blk & 3) * 32; r0 = (blk >> 2) * 32;
  }
  const int x = threadIdx.x, y = threadIdx.y;  // (32, 8)
#pragma unroll
  for (int i = 0; i < 32; i += 8)
    t[y + i][x] = in[(size_t)(r0 + y + i) * C + c0 + x];
  __syncthreads();
#pragma unroll
  for (int i = 0; i < 32; i += 8)
    out[(size_t)(c0 + y + i) * R + r0 + x] = f2bf(t[x][y + i]);
}

// ---------------------------------------------------------------------------
// Split-K GEMM1 partial: P[z] = A(MxKh slice) @ Bt^T, raw f32 sums.
// 64x64 tile, BK=32, 4 waves, 2x2 mfma. z = blockIdx.z selects K-half.
// ---------------------------------------------------------------------------
__global__ __launch_bounds__(256) void gemm_bt_partial(
    const unsigned short* __restrict__ A, const unsigned short* __restrict__ Bt,
    float* __restrict__ P, int M, int N, int K, int KH) {
  __shared__ __align__(16) unsigned short Al[64][40];
  __shared__ __align__(16) unsigned short Bl[64][40];
  const int bm = blockIdx.x * 64, bn = blockIdx.y * 64;
  const int kz = blockIdx.z * KH;
  const int tid = threadIdx.x;
  const int wave = tid >> 6, lane = tid & 63;
  const int wm = (wave & 1) * 32, wn = (wave >> 1) * 32;
  const int ar = tid >> 2, ac = (tid & 3) * 8;
  const int lm = lane & 15, lk = (lane >> 4) * 8;

  f32x4 acc00 = {0.f, 0.f, 0.f, 0.f}, acc01 = {0.f, 0.f, 0.f, 0.f};
  f32x4 acc10 = {0.f, 0.f, 0.f, 0.f}, acc11 = {0.f, 0.f, 0.f, 0.f};

  const unsigned short* pa = A + (size_t)(bm + ar) * K + kz + ac;
  const unsigned short* pb = Bt + (size_t)(bn + ar) * K + kz + ac;

  for (int k0 = 0; k0 < KH; k0 += 32) {
    uint4 va = *(const uint4*)(pa + k0);
    uint4 vb = *(const uint4*)(pb + k0);
    *(uint4*)&Al[ar][ac] = va;
    *(uint4*)&Bl[ar][ac] = vb;
    __syncthreads();
    bf16x8 a0 = *(const bf16x8*)&Al[wm + lm][lk];
    bf16x8 a1 = *(const bf16x8*)&Al[wm + 16 + lm][lk];
    bf16x8 b0 = *(const bf16x8*)&Bl[wn + lm][lk];
    bf16x8 b1 = *(const bf16x8*)&Bl[wn + 16 + lm][lk];
    acc00 = __builtin_amdgcn_mfma_f32_16x16x32_bf16(a0, b0, acc00, 0, 0, 0);
    acc01 = __builtin_amdgcn_mfma_f32_16x16x32_bf16(a0, b1, acc01, 0, 0, 0);
    acc10 = __builtin_amdgcn_mfma_f32_16x16x32_bf16(a1, b0, acc10, 0, 0, 0);
    acc11 = __builtin_amdgcn_mfma_f32_16x16x32_bf16(a1, b1, acc11, 0, 0, 0);
    __syncthreads();
  }

  float* Pz = P + (size_t)blockIdx.z * M * N;
  const int r0 = bm + wm + ((lane >> 4) << 2);
  const int c0 = bn + wn + lm;
  auto emit = [&](f32x4 v, int row0, int col) {
#pragma unroll
    for (int r = 0; r < 4; ++r) Pz[(size_t)(row0 + r) * N + col] = v[r];
  };
  emit(acc00, r0, c0);
  emit(acc10, r0 + 16, c0);
  emit(acc01, r0, c0 + 16);
  emit(acc11, r0 + 16, c0 + 16);
}

// ---------------------------------------------------------------------------
// Fused reduce + GEMM2 + head. A-staging reads split-K partials P0+P1,
// adds b1, exact gelu, packs bf16 (x1 never materialized). Then 64x128
// GEMM2 (K=256), gelu+b2 -> S2 LDS, 2-wide head dot, sigmoid*8+1, *qmask.
// ---------------------------------------------------------------------------
__global__ __launch_bounds__(256) void gemm2_head_kernel(
    const float* __restrict__ P, const unsigned short* __restrict__ Bt,
    const float* __restrict__ b1, const float* __restrict__ b2,
    const float* __restrict__ W3, const float* __restrict__ b3,
    const int* __restrict__ qmask, float* __restrict__ out) {
  __shared__ __align__(16) unsigned short Al[64][40];
  __shared__ __align__(16) unsigned short Bl[128][40];
  __shared__ float S2[64][129];
  __shared__ float w3[256];

  const int bm = blockIdx.x * 64;
  const int tid = threadIdx.x;
  const int wave = tid >> 6, lane = tid & 63;
  const int wm = (wave & 1) * 32, wn = (wave >> 1) * 64;
  const int ar = tid >> 2, ac = (tid & 3) * 8;   // A staging (8 k-elems)
  const int br = tid >> 1, bc = (tid & 1) * 16;  // B staging (2x uint4)
  const int lm = lane & 15, quad = lane >> 4;

  w3[tid] = W3[tid];

  f32x4 acc[2][4];
#pragma unroll
  for (int f = 0; f < 2; ++f)
#pragma unroll
    for (int g = 0; g < 4; ++g) acc[f][g] = f32x4{0.f, 0.f, 0.f, 0.f};

  const float* p0 = P + (size_t)(bm + ar) * 256 + ac;
  const float* p1 = p0 + (size_t)NPAIR * 256;
  const unsigned short* pb = Bt + (size_t)br * 256 + bc;

  for (int k0 = 0; k0 < 256; k0 += 32) {
    float4 u0 = *(const float4*)(p0 + k0);
    float4 u1 = *(const float4*)(p0 + k0 + 4);
    float4 v0 = *(const float4*)(p1 + k0);
    float4 v1 = *(const float4*)(p1 + k0 + 4);
    float4 bb0 = *(const float4*)(b1 + k0 + ac);
    float4 bb1 = *(const float4*)(b1 + k0 + ac + 4);
    const float g0 = gelu(u0.x + v0.x + bb0.x), g1 = gelu(u0.y + v0.y + bb0.y);
    const float g2 = gelu(u0.z + v0.z + bb0.z), g3 = gelu(u0.w + v0.w + bb0.w);
    const float g4 = gelu(u1.x + v1.x + bb1.x), g5 = gelu(u1.y + v1.y + bb1.y);
    const float g6 = gelu(u1.z + v1.z + bb1.z), g7 = gelu(u1.w + v1.w + bb1.w);
    uint4 va;
    va.x = pack2(g0, g1); va.y = pack2(g2, g3);
    va.z = pack2(g4, g5); va.w = pack2(g6, g7);
    uint4 vb0 = *(const uint4*)(pb + k0);
    uint4 vb1 = *(const uint4*)(pb + k0 + 8);
    *(uint4*)&Al[ar][ac] = va;
    *(uint4*)&Bl[br][bc] = vb0;
    *(uint4*)&Bl[br][bc + 8] = vb1;
    __syncthreads();
    bf16x8 a0 = *(const bf16x8*)&Al[wm + lm][quad * 8];
    bf16x8 a1 = *(const bf16x8*)&Al[wm + 16 + lm][quad * 8];
#pragma unroll
    for (int g = 0; g < 4; ++g) {
      bf16x8 bg = *(const bf16x8*)&Bl[wn + g * 16 + lm][quad * 8];
      acc[0][g] = __builtin_amdgcn_mfma_f32_16x16x32_bf16(a0, bg, acc[0][g], 0, 0, 0);
      acc[1][g] = __builtin_amdgcn_mfma_f32_16x16x32_bf16(a1, bg, acc[1][g], 0, 0, 0);
    }
    __syncthreads();
  }

  // gelu + deposit x2 tile into S2. C/D: col = lane&15, row = quad*4+reg.
#pragma unroll
  for (int f = 0; f < 2; ++f)
#pragma unroll
    for (int g = 0; g < 4; ++g) {
      const int col = wn + g * 16 + lm;
#pragma unroll
      for (int r = 0; r < 4; ++r) {
        const int row = wm + f * 16 + quad * 4 + r;
        S2[row][col] = gelu(acc[f][g][r] + b2[col]);
      }
    }
  __syncthreads();

  // Head: threads 0..127, row = t>>1, o = t&1.
  if (tid < 128) {
    const int row = tid >> 1, o = tid & 1;
    float a = b3[o];
#pragma unroll 8
    for (int c = 0; c < 128; ++c) a += S2[row][c] * w3[c * 2 + o];
    const int pair = bm + row;
    const float qmf = (float)qmask[pair];
    out[pair * 2 + o] = ((1.f / (1.f + expf(-a))) * 8.f + 1.f) * qmf;
  }
}

// ---------------------------------------------------------------------------
extern "C" void kernel_launch(void* const* d_in, const int* in_sizes, int n_in,
                              void* d_out, int out_size, void* d_ws,
                              size_t ws_size, hipStream_t stream) {
  const float* hs = (const float*)d_in[0];   // f32 64x512x1024
  const int* spans = (const int*)d_in[1];
  const int* qmask = (const int*)d_in[2];
  const float* W1 = (const float*)d_in[3];   // f32 3072x256
  const float* b1 = (const float*)d_in[4];
  const float* W2 = (const float*)d_in[5];   // f32 256x128
  const float* b2 = (const float*)d_in[6];
  const float* W3 = (const float*)d_in[7];   // f32 128x2
  const float* b3 = (const float*)d_in[8];
  float* out = (float*)d_out;

  const size_t HPAIR_B = 25165824;  // 4096*3072 bf16
  const size_t P_B = 8388608;       // 2 x 4096*256 f32
  const size_t W1T_B = 1572864;

  char* ws = (char*)d_ws;
  size_t off = 0;
  unsigned short* hpair = (unsigned short*)(ws + off); off += HPAIR_B;
  float* P = (float*)(ws + off);                       off += P_B;
  unsigned short* W1T = (unsigned short*)(ws + off);   off += W1T_B;
  unsigned short* W2T = (unsigned short*)(ws + off);

  transpose_two<<<800, dim3(32, 8), 0, stream>>>(W1, W1T, W2, W2T);
  pool_mfma_kernel<<<1024, 256, 0, stream>>>(hs, spans, qmask, hpair);
  gemm_bt_partial<<<dim3(64, 4, 2), 256, 0, stream>>>(hpair, W1T, P, NPAIR,
                                                      256, 3072, 1536);
  gemm2_head_kernel<<<64, 256, 0, stream>>>(P, W2T, b1, b2, W3, b3, qmask,
                                            out);
}

// Round 7
// 248.269 us; speedup vs baseline: 1.0242x; 1.0242x over previous
//
#include <hip/hip_runtime.h>
#include <math.h>

// SpanPairVAHead on MI355X (gfx950).
// Dtype map (established rounds 0-3): ALL float tensors f32, spans int
// (32/64 sniffed on device), OUTPUT f32. Internal activations bf16 for MFMA.
//
// R7: (1) un-fuse gemm2/head (R6 fusion put reduce+gelu on a 64-block kernel
// = 0.25 blocks/CU; R5's separate 1024-block reduce measured better);
// (2) GEMM1 staging via global_load_lds width=16 (m97 ladder rung): unpadded
// Al/Bl[64][32], lane i -> wave LDS base + 16*i (m104 constraint satisfied).
// 5 launches.
//
// B=64, L=512, H=1024, Q=64, VA_H=256. Pairs = B*Q = 4096.

typedef __attribute__((ext_vector_type(4))) float f32x4;
typedef __attribute__((ext_vector_type(8))) short bf16x8;

#define NPAIR 4096
#define LSEQ 512
#define HDIM 1024

#if defined(__has_builtin)
#if __has_builtin(__builtin_amdgcn_global_load_lds)
#define HAVE_GLDS 1
#endif
#endif
#ifndef HAVE_GLDS
#define HAVE_GLDS 0
#endif

// Pack two f32 -> bf16 pair, round-to-nearest (half-up; differs from RNE only
// on exact ties, p~2^-16). v_perm_b32 grabs the two high halves.
__device__ __forceinline__ unsigned int pack2(float lo, float hi) {
  const unsigned int a = __float_as_uint(lo) + 0x8000u;
  const unsigned int b = __float_as_uint(hi) + 0x8000u;
  return __builtin_amdgcn_perm(b, a, 0x07060302u);
}
__device__ __forceinline__ unsigned short f2bf(float f) {
  return (unsigned short)((__float_as_uint(f) + 0x8000u) >> 16);
}
__device__ __forceinline__ float gelu(float x) {
  return 0.5f * x * (1.f + erff(x * 0.70710678118654752f));
}

// ---------------------------------------------------------------------------
// Fused span pooling via MFMA (R6 version). One block per (batch, 64-col
// H-slice): 1024 blocks = 4/CU. Rows 0..63 = asp masks, 64..127 = opi.
// A-frags from span compares in registers; B staged f32->bf16 transposed
// ([n][k]) double-buffered, 1 barrier/iter. Epilogue S[128][68] unions Bl.
// ---------------------------------------------------------------------------
__global__ __launch_bounds__(256, 4) void pool_mfma_kernel(
    const float* __restrict__ hs, const int* __restrict__ spans,
    const int* __restrict__ qmask, unsigned short* __restrict__ hpair) {
  __shared__ __align__(16) unsigned char smem[34816];  // max(2*64*40*2, 128*68*4)
  __shared__ float scl[128];
  typedef unsigned short BlT[64][40];
  BlT* Bl = (BlT*)smem;                  // Bl[2][64][40]
  float(*S)[68] = (float(*)[68])smem;    // S[128][68] (epilogue only)

  const int b = blockIdx.x >> 4;
  const int n0 = (blockIdx.x & 15) * 64;
  const int tid = threadIdx.x;
  const int lane = tid & 63;
  const int lm = lane & 15, quad = lane >> 4;
  const int wm = (tid >> 6) * 32;  // wave's mask-row base

  const bool is64 =
      (spans[1] == 0) && (spans[3] == 0) && (spans[5] == 0) && (spans[7] == 0);

  auto span_of = [&](int r, int& s, int& e) {
    const int q = r & 63, t = r >> 6;
    const int idx = (b * 64 + q) * 4 + t * 2;
    s = is64 ? spans[idx * 2] : spans[idx];
    e = is64 ? spans[idx * 2 + 2] : spans[idx + 1];
    if (s < 2) { s = 1; e = 1; }  // invalid -> [SEP]
  };
  int s0, e0, s1, e1;
  span_of(wm + lm, s0, e0);
  span_of(wm + 16 + lm, s1, e1);

  if (tid < 128) {
    int s, e;
    span_of(tid, s, e);
    const int c = (e >= s) ? (e - s + 1) : 0;
    const float sc = 1.f / (float)(c < 1 ? 1 : c);
    scl[tid] = (qmask[b * 64 + (tid & 63)] != 0) ? sc : 0.f;
  }

  f32x4 acc[2][4];
#pragma unroll
  for (int f = 0; f < 2; ++f)
#pragma unroll
    for (int g = 0; g < 4; ++g) acc[f][g] = f32x4{0.f, 0.f, 0.f, 0.f};

  const float* hsb = hs + (size_t)b * (LSEQ * HDIM);
  const int nl = tid & 63;        // staged column (wave-coalesced)
  const int kw = (tid >> 6) * 8;  // wave's k-offset within 32-chunk

  auto load8 = [&](int kbase, unsigned int (&tmp)[4]) {
    const float* src = hsb + (size_t)(kbase + kw) * HDIM + n0 + nl;
#pragma unroll
    for (int i = 0; i < 4; ++i) {
      const float f0 = src[(size_t)(2 * i) * HDIM];
      const float f1 = src[(size_t)(2 * i + 1) * HDIM];
      tmp[i] = pack2(f0, f1);
    }
  };

  unsigned int tmp[4];
  load8(0, tmp);
  *(uint4*)&Bl[0][nl][kw] = make_uint4(tmp[0], tmp[1], tmp[2], tmp[3]);

  for (int it = 0; it < 16; ++it) {
    const int k0 = it * 32;
    __syncthreads();  // buf[it&1] staged; prior reads of buf[(it+1)&1] done
    if (it < 15) load8(k0 + 32, tmp);

    bf16x8 a0, a1;
#pragma unroll
    for (int j = 0; j < 8; ++j) {
      const int k = k0 + quad * 8 + j;
      a0[j] = (short)((k >= s0 && k <= e0) ? 0x3F80 : 0);
      a1[j] = (short)((k >= s1 && k <= e1) ? 0x3F80 : 0);
    }
    const BlT& Bc = Bl[it & 1];
#pragma unroll
    for (int g = 0; g < 4; ++g) {
      bf16x8 bg = *(const bf16x8*)&Bc[g * 16 + lm][quad * 8];
      acc[0][g] = __builtin_amdgcn_mfma_f32_16x16x32_bf16(a0, bg, acc[0][g], 0, 0, 0);
      acc[1][g] = __builtin_amdgcn_mfma_f32_16x16x32_bf16(a1, bg, acc[1][g], 0, 0, 0);
    }
    if (it < 15) {
      *(uint4*)&Bl[(it + 1) & 1][nl][kw] = make_uint4(tmp[0], tmp[1], tmp[2], tmp[3]);
    }
  }

  __syncthreads();  // all MFMA LDS reads done before S overwrites Bl
  // C/D layout (m89): col = lane&15, row = quad*4 + reg.
#pragma unroll
  for (int f = 0; f < 2; ++f)
#pragma unroll
    for (int g = 0; g < 4; ++g)
#pragma unroll
      for (int r = 0; r < 4; ++r)
        S[wm + f * 16 + quad * 4 + r][g * 16 + lm] = acc[f][g][r];
  __syncthreads();

  // Store h_pair: thread q = tid>>2, 16-col group cg = (tid&3)*16.
  const int q = tid >> 2;
  const int cg = (tid & 3) * 16;
  const float sA = scl[q], sO = scl[64 + q];
  unsigned short* dst = hpair + (size_t)(b * 64 + q) * 3072 + n0 + cg;
#pragma unroll
  for (int h = 0; h < 2; ++h) {
    float a[8], o[8];
#pragma unroll
    for (int i = 0; i < 8; ++i) {
      a[i] = S[q][cg + h * 8 + i] * sA;
      o[i] = S[64 + q][cg + h * 8 + i] * sO;
    }
    uint4 wa, wo, wp;
    wa.x = pack2(a[0], a[1]); wa.y = pack2(a[2], a[3]);
    wa.z = pack2(a[4], a[5]); wa.w = pack2(a[6], a[7]);
    wo.x = pack2(o[0], o[1]); wo.y = pack2(o[2], o[3]);
    wo.z = pack2(o[4], o[5]); wo.w = pack2(o[6], o[7]);
    wp.x = pack2(a[0] * o[0], a[1] * o[1]); wp.y = pack2(a[2] * o[2], a[3] * o[3]);
    wp.z = pack2(a[4] * o[4], a[5] * o[5]); wp.w = pack2(a[6] * o[6], a[7] * o[7]);
    *(uint4*)(dst + h * 8) = wa;
    *(uint4*)(dst + 1024 + h * 8) = wo;
    *(uint4*)(dst + 2048 + h * 8) = wp;
  }
}

// ---------------------------------------------------------------------------
// Both weight transposes in one launch. Blocks 0..767: W1 (3072x256);
// 768..799: W2 (256x128). f32 in -> bf16 out, transposed.
// ---------------------------------------------------------------------------
__global__ void transpose_two(const float* __restrict__ W1,
                              unsigned short* __restrict__ W1T,
                              const float* __restrict__ W2,
                              unsigned short* __restrict__ W2T) {
  __shared__ float t[32][33];
  const float* in;
  unsigned short* out;
  int R, C, c0, r0;
  int blk = blockIdx.x;
  if (blk < 768) {
    in = W1; out = W1T; R = 3072; C = 256;
    c0 = (blk & 7) * 32; r0 = (blk >> 3) * 32;
  } else {
    blk -= 768;
    in = W2; out = W2T; R = 256; C = 128;
    c0 = (blk & 3) * 32; r0 = (blk >> 2) * 32;
  }
  const int x = threadIdx.x, y = threadIdx.y;  // (32, 8)
#pragma unroll
  for (int i = 0; i < 32; i += 8)
    t[y + i][x] = in[(size_t)(r0 + y + i) * C + c0 + x];
  __syncthreads();
#pragma unroll
  for (int i = 0; i < 32; i += 8)
    out[(size_t)(c0 + y + i) * R + r0 + x] = f2bf(t[x][y + i]);
}

// ---------------------------------------------------------------------------
// Split-K GEMM1 partial: P[z] = A(MxKh slice) @ Bt^T, raw f32 sums.
// 64x64 tile, BK=32, 4 waves, 2x2 mfma. Staging via global_load_lds w=16:
// unpadded [64][32] LDS; wave stages 16 rows, lane i -> wavebase + 16*i
// (row = i/4, kcol = (i&3)*8). Frag ds_read_b128 on this layout is
// bank-balanced (8 lanes x 16B per 4-bank group = LDS BW floor).
// ---------------------------------------------------------------------------
__global__ __launch_bounds__(256) void gemm_bt_partial(
    const unsigned short* __restrict__ A, const unsigned short* __restrict__ Bt,
    float* __restrict__ P, int M, int N, int K, int KH) {
  __shared__ __align__(16) unsigned short Al[64][32];
  __shared__ __align__(16) unsigned short Bl[64][32];
  const int bm = blockIdx.x * 64, bn = blockIdx.y * 64;
  const int kz = blockIdx.z * KH;
  const int tid = threadIdx.x;
  const int wave = tid >> 6, lane = tid & 63;
  const int wm = (wave & 1) * 32, wn = (wave >> 1) * 32;
  const int lm = lane & 15, lk = (lane >> 4) * 8;

  const int srow = wave * 16 + (lane >> 2);
  const int scol = (lane & 3) * 8;
  const unsigned short* ga = A + (size_t)(bm + srow) * K + kz + scol;
  const unsigned short* gb = Bt + (size_t)(bn + srow) * K + kz + scol;
  unsigned short* la = &Al[0][0] + wave * 512;  // wave-uniform LDS chunk base
  unsigned short* lb = &Bl[0][0] + wave * 512;

  f32x4 acc00 = {0.f, 0.f, 0.f, 0.f}, acc01 = {0.f, 0.f, 0.f, 0.f};
  f32x4 acc10 = {0.f, 0.f, 0.f, 0.f}, acc11 = {0.f, 0.f, 0.f, 0.f};

  for (int k0 = 0; k0 < KH; k0 += 32) {
#if HAVE_GLDS
    __builtin_amdgcn_global_load_lds(ga + k0, la, 16, 0, 0);
    __builtin_amdgcn_global_load_lds(gb + k0, lb, 16, 0, 0);
#else
    *(uint4*)(la + lane * 8) = *(const uint4*)(ga + k0);
    *(uint4*)(lb + lane * 8) = *(const uint4*)(gb + k0);
#endif
    __syncthreads();  // drains vmcnt (incl. lds-DMA) before frag reads
    bf16x8 a0 = *(const bf16x8*)&Al[wm + lm][lk];
    bf16x8 a1 = *(const bf16x8*)&Al[wm + 16 + lm][lk];
    bf16x8 b0 = *(const bf16x8*)&Bl[wn + lm][lk];
    bf16x8 b1 = *(const bf16x8*)&Bl[wn + 16 + lm][lk];
    acc00 = __builtin_amdgcn_mfma_f32_16x16x32_bf16(a0, b0, acc00, 0, 0, 0);
    acc01 = __builtin_amdgcn_mfma_f32_16x16x32_bf16(a0, b1, acc01, 0, 0, 0);
    acc10 = __builtin_amdgcn_mfma_f32_16x16x32_bf16(a1, b0, acc10, 0, 0, 0);
    acc11 = __builtin_amdgcn_mfma_f32_16x16x32_bf16(a1, b1, acc11, 0, 0, 0);
    __syncthreads();
  }

  float* Pz = P + (size_t)blockIdx.z * M * N;
  const int r0 = bm + wm + ((lane >> 4) << 2);
  const int c0 = bn + wn + lm;
  auto emit = [&](f32x4 v, int row0, int col) {
#pragma unroll
    for (int r = 0; r < 4; ++r) Pz[(size_t)(row0 + r) * N + col] = v[r];
  };
  emit(acc00, r0, c0);
  emit(acc10, r0 + 16, c0);
  emit(acc01, r0, c0 + 16);
  emit(acc11, r0 + 16, c0 + 16);
}

// ---------------------------------------------------------------------------
// Reduce split-K partials + bias + gelu -> x1 bf16. 4096x256 elements,
// 1024 blocks (4/CU) — full-parallel erf, off any GEMM critical path.
// ---------------------------------------------------------------------------
__global__ __launch_bounds__(256) void reduce_bias_gelu(
    const float* __restrict__ P, const float* __restrict__ bias,
    unsigned short* __restrict__ X) {
  const int t = blockIdx.x * 256 + threadIdx.x;  // 0..262143
  const int e = t * 4;
  float4 p0 = *(const float4*)(P + e);
  float4 p1 = *(const float4*)(P + (size_t)NPAIR * 256 + e);
  float4 bs = *(const float4*)(bias + (e & 255));
  const float v0 = gelu(p0.x + p1.x + bs.x);
  const float v1 = gelu(p0.y + p1.y + bs.y);
  const float v2 = gelu(p0.z + p1.z + bs.z);
  const float v3 = gelu(p0.w + p1.w + bs.w);
  uint2 w;
  w.x = pack2(v0, v1);
  w.y = pack2(v2, v3);
  *(uint2*)(X + e) = w;
}

// ---------------------------------------------------------------------------
// GEMM2 + head (R5 version): x1(4096x256 bf16) @ W2T^T, gelu+b2 -> S2 LDS,
// 2-wide head dot with W3, sigmoid*8+1, *qmask -> f32 out.
// ---------------------------------------------------------------------------
__global__ __launch_bounds__(256) void gemm2_head_kernel(
    const unsigned short* __restrict__ A, const unsigned short* __restrict__ Bt,
    const float* __restrict__ b2, const float* __restrict__ W3,
    const float* __restrict__ b3, const int* __restrict__ qmask,
    float* __restrict__ out) {
  __shared__ __align__(16) unsigned short Al[64][40];
  __shared__ __align__(16) unsigned short Bl[128][40];
  __shared__ float S2[64][129];
  __shared__ float w3[256];

  const int bm = blockIdx.x * 64;
  const int tid = threadIdx.x;
  const int wave = tid >> 6, lane = tid & 63;
  const int wm = (wave & 1) * 32, wn = (wave >> 1) * 64;
  const int ar = tid >> 2, ac = (tid & 3) * 8;   // A staging
  const int br = tid >> 1, bc = (tid & 1) * 16;  // B staging (2x uint4)
  const int lm = lane & 15, quad = lane >> 4;

  w3[tid] = W3[tid];

  f32x4 acc[2][4];
#pragma unroll
  for (int f = 0; f < 2; ++f)
#pragma unroll
    for (int g = 0; g < 4; ++g) acc[f][g] = f32x4{0.f, 0.f, 0.f, 0.f};

  const unsigned short* pa = A + (size_t)(bm + ar) * 256 + ac;
  const unsigned short* pb = Bt + (size_t)br * 256 + bc;

  for (int k0 = 0; k0 < 256; k0 += 32) {
    uint4 va = *(const uint4*)(pa + k0);
    uint4 vb0 = *(const uint4*)(pb + k0);
    uint4 vb1 = *(const uint4*)(pb + k0 + 8);
    *(uint4*)&Al[ar][ac] = va;
    *(uint4*)&Bl[br][bc] = vb0;
    *(uint4*)&Bl[br][bc + 8] = vb1;
    __syncthreads();
    bf16x8 a0 = *(const bf16x8*)&Al[wm + lm][quad * 8];
    bf16x8 a1 = *(const bf16x8*)&Al[wm + 16 + lm][quad * 8];
#pragma unroll
    for (int g = 0; g < 4; ++g) {
      bf16x8 bg = *(const bf16x8*)&Bl[wn + g * 16 + lm][quad * 8];
      acc[0][g] = __builtin_amdgcn_mfma_f32_16x16x32_bf16(a0, bg, acc[0][g], 0, 0, 0);
      acc[1][g] = __builtin_amdgcn_mfma_f32_16x16x32_bf16(a1, bg, acc[1][g], 0, 0, 0);
    }
    __syncthreads();
  }

  // gelu + deposit x2 tile into S2. C/D: col = lane&15, row = quad*4+reg.
#pragma unroll
  for (int f = 0; f < 2; ++f)
#pragma unroll
    for (int g = 0; g < 4; ++g) {
      const int col = wn + g * 16 + lm;
#pragma unroll
      for (int r = 0; r < 4; ++r) {
        const int row = wm + f * 16 + quad * 4 + r;
        S2[row][col] = gelu(acc[f][g][r] + b2[col]);
      }
    }
  __syncthreads();

  // Head: threads 0..127, row = t>>1, o = t&1.
  if (tid < 128) {
    const int row = tid >> 1, o = tid & 1;
    float a = b3[o];
#pragma unroll 8
    for (int c = 0; c < 128; ++c) a += S2[row][c] * w3[c * 2 + o];
    const int pair = bm + row;
    const float qmf = (float)qmask[pair];
    out[pair * 2 + o] = ((1.f / (1.f + expf(-a))) * 8.f + 1.f) * qmf;
  }
}

// ---------------------------------------------------------------------------
extern "C" void kernel_launch(void* const* d_in, const int* in_sizes, int n_in,
                              void* d_out, int out_size, void* d_ws,
                              size_t ws_size, hipStream_t stream) {
  const float* hs = (const float*)d_in[0];   // f32 64x512x1024
  const int* spans = (const int*)d_in[1];
  const int* qmask = (const int*)d_in[2];
  const float* W1 = (const float*)d_in[3];   // f32 3072x256
  const float* b1 = (const float*)d_in[4];
  const float* W2 = (const float*)d_in[5];   // f32 256x128
  const float* b2 = (const float*)d_in[6];
  const float* W3 = (const float*)d_in[7];   // f32 128x2
  const float* b3 = (const float*)d_in[8];
  float* out = (float*)d_out;

  const size_t HPAIR_B = 25165824;  // 4096*3072 bf16
  const size_t X1_B = 2097152;      // 4096*256 bf16
  const size_t P_B = 8388608;       // 2 x 4096*256 f32
  const size_t W1T_B = 1572864;

  char* ws = (char*)d_ws;
  size_t off = 0;
  unsigned short* hpair = (unsigned short*)(ws + off); off += HPAIR_B;
  unsigned short* x1 = (unsigned short*)(ws + off);    off += X1_B;
  float* P = (float*)(ws + off);                       off += P_B;
  unsigned short* W1T = (unsigned short*)(ws + off);   off += W1T_B;
  unsigned short* W2T = (unsigned short*)(ws + off);

  transpose_two<<<800, dim3(32, 8), 0, stream>>>(W1, W1T, W2, W2T);
  pool_mfma_kernel<<<1024, 256, 0, stream>>>(hs, spans, qmask, hpair);
  gemm_bt_partial<<<dim3(64, 4, 2), 256, 0, stream>>>(hpair, W1T, P, NPAIR,
                                                      256, 3072, 1536);
  reduce_bias_gelu<<<1024, 256, 0, stream>>>(P, b1, x1);
  gemm2_head_kernel<<<64, 256, 0, stream>>>(x1, W2T, b2, W3, b3, qmask, out);
}